// Round 1
// baseline (331.019 us; speedup 1.0000x reference)
//
#include <hip/hip_runtime.h>
#include <math.h>

#define HW2D 25600      // 160*160
#define NB 8
#define NC 256
#define CR 64
#define H_ 160
#define W_ 160

// ---------------- transpose weights: wT[c*64+o] = w[o*256+c] ----------------
__global__ __launch_bounds__(256) void k_wt(const float* __restrict__ w,
                                            float* __restrict__ wT) {
    int i = blockIdx.x * 256 + threadIdx.x;   // i < 64*256
    if (i >= CR * NC) return;
    int o = i / NC, c = i - o * NC;
    wT[c * CR + o] = w[i];
}

// ---------------- channel reduction: y0[b,o,px] = sum_c wT[c,o]*x[b,c,px] ----
__global__ __launch_bounds__(256) void k_reduce(const float* __restrict__ x,
                                                const float* __restrict__ wT,
                                                float* __restrict__ y0) {
    int pxg = blockIdx.x * 256 + threadIdx.x;   // 0..204799
    int b = pxg / HW2D;
    int px = pxg - b * HW2D;
    const float* xp = x + (size_t)b * NC * HW2D + px;
    float acc[CR];
#pragma unroll
    for (int o = 0; o < CR; ++o) acc[o] = 0.f;
#pragma unroll 4
    for (int c = 0; c < NC; ++c) {
        float xv = xp[(size_t)c * HW2D];
        const float* wr = wT + c * CR;   // uniform -> scalar loads
#pragma unroll
        for (int o = 0; o < CR; ++o) acc[o] = fmaf(wr[o], xv, acc[o]);
    }
    float* yp = y0 + (size_t)b * CR * HW2D + px;
#pragma unroll
    for (int o = 0; o < CR; ++o) yp[(size_t)o * HW2D] = acc[o];
}

// ---------------- per-(b,c) sum / sumsq over HW ------------------------------
__global__ __launch_bounds__(256) void k_stats(const float* __restrict__ y0,
                                               float* __restrict__ sum,
                                               float* __restrict__ sumsq) {
    int bc = blockIdx.x;  // b*64+c
    const float* yp = y0 + (size_t)bc * HW2D;
    float s = 0.f, sq = 0.f;
    for (int i = threadIdx.x; i < HW2D; i += 256) {
        float v = yp[i];
        s += v;
        sq = fmaf(v, v, sq);
    }
#pragma unroll
    for (int off = 32; off; off >>= 1) {
        s += __shfl_xor(s, off, 64);
        sq += __shfl_xor(sq, off, 64);
    }
    __shared__ float ls[4], lq[4];
    int wid = threadIdx.x >> 6;
    if ((threadIdx.x & 63) == 0) { ls[wid] = s; lq[wid] = sq; }
    __syncthreads();
    if (threadIdx.x == 0) {
        sum[bc]   = ls[0] + ls[1] + ls[2] + ls[3];
        sumsq[bc] = lq[0] + lq[1] + lq[2] + lq[3];
    }
}

// ---------------- GN finalize + gate MLP + fused weights ---------------------
__global__ __launch_bounds__(512) void k_gate(const float* __restrict__ sum,
                                              const float* __restrict__ sumsq,
                                              const float* __restrict__ gn_scale,
                                              const float* __restrict__ gn_bias,
                                              const float* __restrict__ w1,
                                              const float* __restrict__ b1,
                                              const float* __restrict__ w2,
                                              const float* __restrict__ b2,
                                              const float* __restrict__ fw,
                                              float* __restrict__ sA,
                                              float* __restrict__ sB,
                                              float* __restrict__ wef) {
    int t = threadIdx.x;          // 0..511 = b*64+c
    int b = t >> 6, c = t & 63;
    __shared__ float sh_sum[512], sh_sq[512], sh_p[512], sh_h[128];
    float s = sum[t], sq = sumsq[t];
    sh_sum[t] = s;
    sh_sq[t] = sq;
    __syncthreads();
    // group stats: group of c is c/8 (8 channels each)
    int base = (t & ~7);          // b*64 + (c & ~7)
    float gs = 0.f, gq = 0.f;
#pragma unroll
    for (int i = 0; i < 8; ++i) { gs += sh_sum[base + i]; gq += sh_sq[base + i]; }
    const float invN = 1.0f / (8.0f * HW2D);
    float mean = gs * invN;
    float var = gq * invN - mean * mean;
    float rstd = rsqrtf(var + 1e-5f);
    float A = rstd * gn_scale[c];
    float Bv = gn_bias[c] - mean * A;
    sA[t] = A;
    sB[t] = Bv;
    float chmean = s * (1.0f / HW2D);
    sh_p[t] = chmean * A + Bv;    // post-affine per-channel spatial mean
    __syncthreads();
    if (t < 128) {                // hdn[b,j], 8*16
        int bb = t >> 4, j = t & 15;
        float h = b1[j];
        for (int i = 0; i < 64; ++i) h = fmaf(sh_p[bb * 64 + i], w1[j * 64 + i], h);
        sh_h[t] = fmaxf(h, 0.f);
    }
    __syncthreads();
    float gacc = b2[c];
#pragma unroll
    for (int j = 0; j < 16; ++j) gacc = fmaf(sh_h[b * 16 + j], w2[c * 16 + j], gacc);
    float gamma = 1.0f / (1.0f + expf(-gacc));
    wef[t] = fw[c] + gamma * fw[CR + c];
}

// ---------------- stencil + channel reduce -> a ------------------------------
// tiles: 16 rows x 32 cols; halo 18x34 in LDS
__global__ __launch_bounds__(256) void k_stencil(const float* __restrict__ y0,
                                                 const float* __restrict__ sA,
                                                 const float* __restrict__ sB,
                                                 const float* __restrict__ wef,
                                                 float* __restrict__ abuf) {
    const int tw = blockIdx.x * 32, th = blockIdx.y * 16, b = blockIdx.z;
    __shared__ float sm[18 * 34];
    int t = threadIdx.x;
    int col = t & 31, row0 = t >> 5;   // 8 row-slots, each thread does rows row0, row0+8
    float logit0 = 0.f, logit1 = 0.f;
    const float* yb = y0 + (size_t)b * CR * HW2D;
    for (int c = 0; c < CR; ++c) {
        float A = sA[b * 64 + c], Bv = sB[b * 64 + c], wf = wef[b * 64 + c];
        const float* yc = yb + (size_t)c * HW2D;
        __syncthreads();   // protect previous iteration's reads
        for (int i = t; i < 18 * 34; i += 256) {
            int r = i / 34, cc = i - r * 34;
            int gh = th + r - 1, gw = tw + cc - 1;
            float v = 0.f;   // zero-pad AFTER affine (pad applies to post-affine y)
            if ((unsigned)gh < 160u && (unsigned)gw < 160u)
                v = fmaf(A, yc[gh * W_ + gw], Bv);
            sm[i] = v;
        }
        __syncthreads();
#pragma unroll
        for (int k = 0; k < 2; ++k) {
            int r = row0 + k * 8;                 // tile row 0..15
            const float* p = sm + r * 34 + col;   // top-left of 3x3 around (r+1,col+1)
            float v00 = p[0],  v01 = p[1],  v02 = p[2];
            float v10 = p[34], v11 = p[35], v12 = p[36];
            float v20 = p[68], v21 = p[69], v22 = p[70];
            float mu = (v00 + v01 + v02 + v10 + v11 + v12 + v20 + v21 + v22) * (1.f / 9.f);
            float gx = (v00 - v02 + 2.f * (v10 - v12) + v20 - v22) * 0.25f;
            float gy = (v00 - v20 + 2.f * (v01 - v21) + v02 - v22) * 0.25f;
            float ratio = fabsf(v11 - mu) / (fabsf(gx) + fabsf(gy) + 1e-4f);
            ratio = fminf(ratio, 2.f);
            float kap = 1.f - ratio;              // already in [-1,1]
            if (k == 0) logit0 = fmaf(wf, kap, logit0);
            else        logit1 = fmaf(wf, kap, logit1);
        }
    }
    float* ab = abuf + (size_t)b * HW2D;
    int r0 = th + row0, c0 = tw + col;
    ab[r0 * W_ + c0]       = 1.f / (1.f + expf(-logit0));
    ab[(r0 + 8) * W_ + c0] = 1.f / (1.f + expf(-logit1));
}

// ---------------- out = x * (1 + 0.1*a) --------------------------------------
__global__ __launch_bounds__(256) void k_apply(const float* __restrict__ x,
                                               const float* __restrict__ abuf,
                                               float* __restrict__ out, int n4) {
    int stride = gridDim.x * 256;
    for (int i = blockIdx.x * 256 + threadIdx.x; i < n4; i += stride) {
        float4 xv = ((const float4*)x)[i];
        int e = i * 4;                       // < 2^31
        int b = e / (NC * HW2D);
        int px = e % HW2D;
        float4 av = *(const float4*)(abuf + b * HW2D + px);
        float4 ov;
        ov.x = xv.x * fmaf(0.1f, av.x, 1.f);
        ov.y = xv.y * fmaf(0.1f, av.y, 1.f);
        ov.z = xv.z * fmaf(0.1f, av.z, 1.f);
        ov.w = xv.w * fmaf(0.1f, av.w, 1.f);
        ((float4*)out)[i] = ov;
    }
}

extern "C" void kernel_launch(void* const* d_in, const int* in_sizes, int n_in,
                              void* d_out, int out_size, void* d_ws, size_t ws_size,
                              hipStream_t stream) {
    const float* x   = (const float*)d_in[0];
    const float* rw  = (const float*)d_in[1];
    const float* gns = (const float*)d_in[2];
    const float* gnb = (const float*)d_in[3];
    const float* w1  = (const float*)d_in[4];
    const float* b1  = (const float*)d_in[5];
    const float* w2  = (const float*)d_in[6];
    const float* b2  = (const float*)d_in[7];
    const float* fw  = (const float*)d_in[8];
    float* out = (float*)d_out;

    float* ws    = (float*)d_ws;
    float* y0    = ws;                       // 13,107,200
    float* abuf  = y0 + (size_t)NB * CR * HW2D;  // 204,800
    float* sum   = abuf + (size_t)NB * HW2D;     // 512
    float* sumsq = sum + 512;
    float* sA    = sumsq + 512;
    float* sB    = sA + 512;
    float* wef   = sB + 512;
    float* wT    = wef + 512;                // 16384

    hipLaunchKernelGGL(k_wt,      dim3(64),       dim3(256), 0, stream, rw, wT);
    hipLaunchKernelGGL(k_reduce,  dim3(800),      dim3(256), 0, stream, x, wT, y0);
    hipLaunchKernelGGL(k_stats,   dim3(512),      dim3(256), 0, stream, y0, sum, sumsq);
    hipLaunchKernelGGL(k_gate,    dim3(1),        dim3(512), 0, stream,
                       sum, sumsq, gns, gnb, w1, b1, w2, b2, fw, sA, sB, wef);
    hipLaunchKernelGGL(k_stencil, dim3(5, 10, 8), dim3(256), 0, stream, y0, sA, sB, wef, abuf);
    hipLaunchKernelGGL(k_apply,   dim3(4096),     dim3(256), 0, stream, x, abuf, out,
                       (NB * NC * HW2D) / 4);
}

// Round 2
// 210.258 us; speedup vs baseline: 1.5743x; 1.5743x over previous
//
#include <hip/hip_runtime.h>
#include <math.h>

#define HW2D 25600      // 160*160
#define NB 8
#define NC 256
#define CR 64
#define H_ 160
#define W_ 160

typedef short bf16x8 __attribute__((ext_vector_type(8)));
typedef float f32x4 __attribute__((ext_vector_type(4)));

__device__ __forceinline__ short f2bf(float f) {
    union { float f; unsigned u; } v; v.f = f;
    unsigned r = (v.u + 0x7FFFu + ((v.u >> 16) & 1u)) >> 16;   // RNE
    return (short)r;
}
__device__ __forceinline__ float bf2f(unsigned short b) {
    union { unsigned u; float f; } v; v.u = ((unsigned)b) << 16;
    return v.f;
}

// ---- pack reduce_w into MFMA A-fragment order: aPack[(s*4+m)*64+lane][8] ----
__global__ __launch_bounds__(256) void k_pack(const float* __restrict__ rw,
                                              short* __restrict__ aPack) {
    int t = blockIdx.x * 256 + threadIdx.x;   // 0..2047
    if (t >= 2048) return;
    int s = t >> 8, m = (t >> 6) & 3, lane = t & 63;
    int row = m * 16 + (lane & 15);           // output o within [0,64)
    int k0 = s * 32 + (lane >> 4) * 8;        // channel c
    short* dst = aPack + ((size_t)((s * 4 + m) * 64 + lane)) * 8;
#pragma unroll
    for (int j = 0; j < 8; ++j)
        dst[j] = f2bf(rw[row * NC + k0 + j]);
}

// ---- y0[b,o,px] = sum_c W[o,c]*x[b,c,px] via bf16 MFMA; y0 stored as bf16 ---
__global__ __launch_bounds__(256) void k_rmfma(const float* __restrict__ x,
                                               const short* __restrict__ aPack,
                                               unsigned short* __restrict__ y0) {
    int wave = threadIdx.x >> 6, lane = threadIdx.x & 63;
    int blk = blockIdx.x;
    int b = blk / 200;
    int pxb = (blk - b * 200) * 128 + wave * 32;   // 32 px per wave
    int l15 = lane & 15, kg = lane >> 4;
    const float* xb = x + (size_t)b * NC * HW2D;
    f32x4 acc[4][2];
    f32x4 zz = {0.f, 0.f, 0.f, 0.f};
#pragma unroll
    for (int m = 0; m < 4; ++m)
#pragma unroll
        for (int n = 0; n < 2; ++n) acc[m][n] = zz;
    const bf16x8* ap = (const bf16x8*)aPack + lane;
#pragma unroll
    for (int s = 0; s < 8; ++s) {
        bf16x8 a0 = ap[(s * 4 + 0) * 64];
        bf16x8 a1 = ap[(s * 4 + 1) * 64];
        bf16x8 a2 = ap[(s * 4 + 2) * 64];
        bf16x8 a3 = ap[(s * 4 + 3) * 64];
        const float* xk = xb + (size_t)(s * 32 + kg * 8) * HW2D + pxb + l15;
        bf16x8 b0, b1;
#pragma unroll
        for (int j = 0; j < 8; ++j) {
            b0[j] = f2bf(xk[(size_t)j * HW2D]);
            b1[j] = f2bf(xk[(size_t)j * HW2D + 16]);
        }
        acc[0][0] = __builtin_amdgcn_mfma_f32_16x16x32_bf16(a0, b0, acc[0][0], 0, 0, 0);
        acc[0][1] = __builtin_amdgcn_mfma_f32_16x16x32_bf16(a0, b1, acc[0][1], 0, 0, 0);
        acc[1][0] = __builtin_amdgcn_mfma_f32_16x16x32_bf16(a1, b0, acc[1][0], 0, 0, 0);
        acc[1][1] = __builtin_amdgcn_mfma_f32_16x16x32_bf16(a1, b1, acc[1][1], 0, 0, 0);
        acc[2][0] = __builtin_amdgcn_mfma_f32_16x16x32_bf16(a2, b0, acc[2][0], 0, 0, 0);
        acc[2][1] = __builtin_amdgcn_mfma_f32_16x16x32_bf16(a2, b1, acc[2][1], 0, 0, 0);
        acc[3][0] = __builtin_amdgcn_mfma_f32_16x16x32_bf16(a3, b0, acc[3][0], 0, 0, 0);
        acc[3][1] = __builtin_amdgcn_mfma_f32_16x16x32_bf16(a3, b1, acc[3][1], 0, 0, 0);
    }
    // C/D layout: col = lane&15, row = (lane>>4)*4 + i  [verified m89]
    unsigned short* yb = y0 + (size_t)b * CR * HW2D + pxb + l15;
#pragma unroll
    for (int m = 0; m < 4; ++m)
#pragma unroll
        for (int n = 0; n < 2; ++n)
#pragma unroll
            for (int i = 0; i < 4; ++i) {
                int o = m * 16 + kg * 4 + i;
                yb[(size_t)o * HW2D + n * 16] = (unsigned short)f2bf(acc[m][n][i]);
            }
}

// ---------------- per-(b,c) sum / sumsq over HW (bf16 input) -----------------
__global__ __launch_bounds__(256) void k_stats(const unsigned short* __restrict__ y0,
                                               float* __restrict__ sum,
                                               float* __restrict__ sumsq) {
    int bc = blockIdx.x;  // b*64+c
    const unsigned short* yp = y0 + (size_t)bc * HW2D;
    float s = 0.f, sq = 0.f;
    for (int i = threadIdx.x; i < HW2D / 4; i += 256) {
        ushort4 v = ((const ushort4*)yp)[i];
        float f0 = bf2f(v.x), f1 = bf2f(v.y), f2 = bf2f(v.z), f3 = bf2f(v.w);
        s += f0 + f1 + f2 + f3;
        sq = fmaf(f0, f0, sq); sq = fmaf(f1, f1, sq);
        sq = fmaf(f2, f2, sq); sq = fmaf(f3, f3, sq);
    }
#pragma unroll
    for (int off = 32; off; off >>= 1) {
        s += __shfl_xor(s, off, 64);
        sq += __shfl_xor(sq, off, 64);
    }
    __shared__ float ls[4], lq[4];
    int wid = threadIdx.x >> 6;
    if ((threadIdx.x & 63) == 0) { ls[wid] = s; lq[wid] = sq; }
    __syncthreads();
    if (threadIdx.x == 0) {
        sum[bc]   = ls[0] + ls[1] + ls[2] + ls[3];
        sumsq[bc] = lq[0] + lq[1] + lq[2] + lq[3];
    }
}

// ---------------- GN finalize + gate MLP + fused weights ---------------------
__global__ __launch_bounds__(512) void k_gate(const float* __restrict__ sum,
                                              const float* __restrict__ sumsq,
                                              const float* __restrict__ gn_scale,
                                              const float* __restrict__ gn_bias,
                                              const float* __restrict__ w1,
                                              const float* __restrict__ b1,
                                              const float* __restrict__ w2,
                                              const float* __restrict__ b2,
                                              const float* __restrict__ fw,
                                              float* __restrict__ sA,
                                              float* __restrict__ sB,
                                              float* __restrict__ wef) {
    int t = threadIdx.x;          // 0..511 = b*64+c
    int b = t >> 6, c = t & 63;
    __shared__ float sh_sum[512], sh_sq[512], sh_p[512], sh_h[128];
    float s = sum[t], sq = sumsq[t];
    sh_sum[t] = s;
    sh_sq[t] = sq;
    __syncthreads();
    int base = (t & ~7);
    float gs = 0.f, gq = 0.f;
#pragma unroll
    for (int i = 0; i < 8; ++i) { gs += sh_sum[base + i]; gq += sh_sq[base + i]; }
    const float invN = 1.0f / (8.0f * HW2D);
    float mean = gs * invN;
    float var = gq * invN - mean * mean;
    float rstd = rsqrtf(var + 1e-5f);
    float A = rstd * gn_scale[c];
    float Bv = gn_bias[c] - mean * A;
    sA[t] = A;
    sB[t] = Bv;
    float chmean = s * (1.0f / HW2D);
    sh_p[t] = chmean * A + Bv;
    __syncthreads();
    if (t < 128) {
        int bb = t >> 4, j = t & 15;
        float h = b1[j];
        for (int i = 0; i < 64; ++i) h = fmaf(sh_p[bb * 64 + i], w1[j * 64 + i], h);
        sh_h[t] = fmaxf(h, 0.f);
    }
    __syncthreads();
    float gacc = b2[c];
#pragma unroll
    for (int j = 0; j < 16; ++j) gacc = fmaf(sh_h[b * 16 + j], w2[c * 16 + j], gacc);
    float gamma = 1.0f / (1.0f + expf(-gacc));
    wef[t] = fw[c] + gamma * fw[CR + c];
}

// ------- stencil + partial channel reduce (32 channels per block) ------------
// tiles: 16 rows x 32 cols; halo 18x34 in LDS, double-buffered
__global__ __launch_bounds__(256) void k_stencil(const unsigned short* __restrict__ y0,
                                                 const float* __restrict__ sA,
                                                 const float* __restrict__ sB,
                                                 const float* __restrict__ wef,
                                                 float* __restrict__ pbuf) {
    const int tw = blockIdx.x * 32, th = blockIdx.y * 16;
    const int half = blockIdx.z & 1, b = blockIdx.z >> 1;
    const int c0 = half * 32;
    __shared__ float sm[2][18 * 34];
    int t = threadIdx.x;
    int col = t & 31, row0 = t >> 5;
    float logit0 = 0.f, logit1 = 0.f;
    const unsigned short* yb = y0 + (size_t)b * CR * HW2D;

    auto stage = [&](int c, int buf) {
        const unsigned short* yc = yb + (size_t)c * HW2D;
        float A = sA[b * 64 + c], Bv = sB[b * 64 + c];
        for (int i = t; i < 18 * 34; i += 256) {
            int r = i / 34, cc = i - r * 34;
            int gh = th + r - 1, gw = tw + cc - 1;
            float v = 0.f;   // zero-pad AFTER affine
            if ((unsigned)gh < 160u && (unsigned)gw < 160u)
                v = fmaf(A, bf2f(yc[gh * W_ + gw]), Bv);
            sm[buf][i] = v;
        }
    };
    stage(c0, 0);
    __syncthreads();
    for (int ci = 0; ci < 32; ++ci) {
        int c = c0 + ci;
        if (ci < 31) stage(c + 1, (ci + 1) & 1);
        float wf = wef[b * 64 + c];
        const float* smc = sm[ci & 1];
#pragma unroll
        for (int k = 0; k < 2; ++k) {
            int r = row0 + k * 8;
            const float* p = smc + r * 34 + col;
            float v00 = p[0],  v01 = p[1],  v02 = p[2];
            float v10 = p[34], v11 = p[35], v12 = p[36];
            float v20 = p[68], v21 = p[69], v22 = p[70];
            float mu = (v00 + v01 + v02 + v10 + v11 + v12 + v20 + v21 + v22) * (1.f / 9.f);
            float gx = (v00 - v02 + 2.f * (v10 - v12) + v20 - v22) * 0.25f;
            float gy = (v00 - v20 + 2.f * (v01 - v21) + v02 - v22) * 0.25f;
            float ratio = fminf(fabsf(v11 - mu) / (fabsf(gx) + fabsf(gy) + 1e-4f), 2.f);
            float kap = 1.f - ratio;
            if (k == 0) logit0 = fmaf(wf, kap, logit0);
            else        logit1 = fmaf(wf, kap, logit1);
        }
        __syncthreads();
    }
    float* pb = pbuf + ((size_t)half * NB + b) * HW2D;
    int r0 = th + row0, cpx = tw + col;
    pb[r0 * W_ + cpx]       = logit0;
    pb[(r0 + 8) * W_ + cpx] = logit1;
}

// ---------------- a = sigmoid(p0 + p1) ---------------------------------------
__global__ __launch_bounds__(256) void k_fuse(const float* __restrict__ pbuf,
                                              float* __restrict__ abuf) {
    int i = blockIdx.x * 256 + threadIdx.x;   // < NB*HW2D
    if (i >= NB * HW2D) return;
    float l = pbuf[i] + pbuf[NB * HW2D + i];
    abuf[i] = 1.f / (1.f + expf(-l));
}

// ---------------- out = x * (1 + 0.1*a) --------------------------------------
__global__ __launch_bounds__(256) void k_apply(const float* __restrict__ x,
                                               const float* __restrict__ abuf,
                                               float* __restrict__ out, int n4) {
    int stride = gridDim.x * 256;
    for (int i = blockIdx.x * 256 + threadIdx.x; i < n4; i += stride) {
        float4 xv = ((const float4*)x)[i];
        int e = i * 4;
        int b = e / (NC * HW2D);
        int px = e % HW2D;
        float4 av = *(const float4*)(abuf + b * HW2D + px);
        float4 ov;
        ov.x = xv.x * fmaf(0.1f, av.x, 1.f);
        ov.y = xv.y * fmaf(0.1f, av.y, 1.f);
        ov.z = xv.z * fmaf(0.1f, av.z, 1.f);
        ov.w = xv.w * fmaf(0.1f, av.w, 1.f);
        ((float4*)out)[i] = ov;
    }
}

extern "C" void kernel_launch(void* const* d_in, const int* in_sizes, int n_in,
                              void* d_out, int out_size, void* d_ws, size_t ws_size,
                              hipStream_t stream) {
    const float* x   = (const float*)d_in[0];
    const float* rw  = (const float*)d_in[1];
    const float* gns = (const float*)d_in[2];
    const float* gnb = (const float*)d_in[3];
    const float* w1  = (const float*)d_in[4];
    const float* b1  = (const float*)d_in[5];
    const float* w2  = (const float*)d_in[6];
    const float* b2  = (const float*)d_in[7];
    const float* fw  = (const float*)d_in[8];
    float* out = (float*)d_out;

    float* ws    = (float*)d_ws;
    float* pbuf  = ws;                               // 2*8*25600 = 409600 f
    float* abuf  = pbuf + 2 * (size_t)NB * HW2D;     // 204800 f
    float* sum   = abuf + (size_t)NB * HW2D;         // 512
    float* sumsq = sum + 512;
    float* sA    = sumsq + 512;
    float* sB    = sA + 512;
    float* wef   = sB + 512;
    short* aPack = (short*)(wef + 512);              // 16384 shorts (32 KB)
    unsigned short* y0 = (unsigned short*)(aPack + 16384);  // 13,107,200 ushorts

    hipLaunchKernelGGL(k_pack,    dim3(8),        dim3(256), 0, stream, rw, aPack);
    hipLaunchKernelGGL(k_rmfma,   dim3(1600),     dim3(256), 0, stream, x, aPack, y0);
    hipLaunchKernelGGL(k_stats,   dim3(512),      dim3(256), 0, stream, y0, sum, sumsq);
    hipLaunchKernelGGL(k_gate,    dim3(1),        dim3(512), 0, stream,
                       sum, sumsq, gns, gnb, w1, b1, w2, b2, fw, sA, sB, wef);
    hipLaunchKernelGGL(k_stencil, dim3(5, 10, 16), dim3(256), 0, stream, y0, sA, sB, wef, pbuf);
    hipLaunchKernelGGL(k_fuse,    dim3(800),      dim3(256), 0, stream, pbuf, abuf);
    hipLaunchKernelGGL(k_apply,   dim3(4096),     dim3(256), 0, stream, x, abuf, out,
                       (NB * NC * HW2D) / 4);
}

// Round 3
// 173.070 us; speedup vs baseline: 1.9126x; 1.2149x over previous
//
#include <hip/hip_runtime.h>
#include <hip/hip_bf16.h>
#include <math.h>

#define HW2D 25600      // 160*160
#define NB 8
#define NC 256
#define CR 64
#define H_ 160
#define W_ 160

typedef short bf16x8 __attribute__((ext_vector_type(8)));
typedef float f32x4 __attribute__((ext_vector_type(4)));

__device__ __forceinline__ short f2bf(float f) {
    __hip_bfloat16 h = __float2bfloat16(f);   // compiler emits v_cvt_pk_bf16_f32 pairs
    return *reinterpret_cast<short*>(&h);
}
__device__ __forceinline__ float bf2f(unsigned short b) {
    union { unsigned u; float f; } v; v.u = ((unsigned)b) << 16;
    return v.f;
}

// ---- pack reduce_w into MFMA A-fragment order: aPack[(s*4+m)*64+lane][8] ----
__global__ __launch_bounds__(256) void k_pack(const float* __restrict__ rw,
                                              short* __restrict__ aPack) {
    int t = blockIdx.x * 256 + threadIdx.x;   // 0..2047
    if (t >= 2048) return;
    int s = t >> 8, m = (t >> 6) & 3, lane = t & 63;
    int row = m * 16 + (lane & 15);           // output o within [0,64)
    int k0 = s * 32 + (lane >> 4) * 8;        // channel c
    short* dst = aPack + ((size_t)((s * 4 + m) * 64 + lane)) * 8;
#pragma unroll
    for (int j = 0; j < 8; ++j)
        dst[j] = f2bf(rw[row * NC + k0 + j]);
}

// ---- y0[b,o,px] = sum_c W[o,c]*x[b,c,px] via bf16 MFMA; y0 stored as bf16 ---
__global__ __launch_bounds__(256) void k_rmfma(const float* __restrict__ x,
                                               const short* __restrict__ aPack,
                                               unsigned short* __restrict__ y0) {
    int wave = __builtin_amdgcn_readfirstlane(threadIdx.x >> 6);  // SGPR wave id
    int lane = threadIdx.x & 63;
    int blk = blockIdx.x;
    int b = blk / 200;
    int pxb = (blk - b * 200) * 128 + wave * 32;   // wave-uniform (SGPR)
    int l15 = lane & 15, kg = lane >> 4;
    int laneoff = kg * 8 * HW2D + l15;             // per-lane 32-bit offset
    const float* xw = x + (size_t)b * NC * HW2D + pxb;   // SGPR base
    f32x4 acc[4][2];
    f32x4 zz = {0.f, 0.f, 0.f, 0.f};
#pragma unroll
    for (int m = 0; m < 4; ++m)
#pragma unroll
        for (int n = 0; n < 2; ++n) acc[m][n] = zz;
    const bf16x8* ap = (const bf16x8*)aPack + lane;
#pragma unroll
    for (int s = 0; s < 8; ++s) {
        bf16x8 a0 = ap[(s * 4 + 0) * 64];
        bf16x8 a1 = ap[(s * 4 + 1) * 64];
        bf16x8 a2 = ap[(s * 4 + 2) * 64];
        bf16x8 a3 = ap[(s * 4 + 3) * 64];
        const float* xs = xw + s * 32 * HW2D + laneoff;
        bf16x8 b0, b1;
#pragma unroll
        for (int j = 0; j < 8; ++j) {
            b0[j] = f2bf(xs[j * HW2D]);
            b1[j] = f2bf(xs[j * HW2D + 16]);
        }
        acc[0][0] = __builtin_amdgcn_mfma_f32_16x16x32_bf16(a0, b0, acc[0][0], 0, 0, 0);
        acc[0][1] = __builtin_amdgcn_mfma_f32_16x16x32_bf16(a0, b1, acc[0][1], 0, 0, 0);
        acc[1][0] = __builtin_amdgcn_mfma_f32_16x16x32_bf16(a1, b0, acc[1][0], 0, 0, 0);
        acc[1][1] = __builtin_amdgcn_mfma_f32_16x16x32_bf16(a1, b1, acc[1][1], 0, 0, 0);
        acc[2][0] = __builtin_amdgcn_mfma_f32_16x16x32_bf16(a2, b0, acc[2][0], 0, 0, 0);
        acc[2][1] = __builtin_amdgcn_mfma_f32_16x16x32_bf16(a2, b1, acc[2][1], 0, 0, 0);
        acc[3][0] = __builtin_amdgcn_mfma_f32_16x16x32_bf16(a3, b0, acc[3][0], 0, 0, 0);
        acc[3][1] = __builtin_amdgcn_mfma_f32_16x16x32_bf16(a3, b1, acc[3][1], 0, 0, 0);
    }
    // C/D layout: col = lane&15, row = (lane>>4)*4 + i
    unsigned short* yw = y0 + (size_t)b * CR * HW2D + pxb;   // SGPR base
#pragma unroll
    for (int m = 0; m < 4; ++m)
#pragma unroll
        for (int n = 0; n < 2; ++n)
#pragma unroll
            for (int i = 0; i < 4; ++i) {
                int o = m * 16 + kg * 4 + i;
                yw[o * HW2D + n * 16 + l15] = (unsigned short)f2bf(acc[m][n][i]);
            }
}

// ---------------- per-(b,c) sum / sumsq over HW (bf16 input) -----------------
__global__ __launch_bounds__(256) void k_stats(const unsigned short* __restrict__ y0,
                                               float* __restrict__ sum,
                                               float* __restrict__ sumsq) {
    int bc = blockIdx.x;  // b*64+c
    const unsigned short* yp = y0 + (size_t)bc * HW2D;
    float s = 0.f, sq = 0.f;
    for (int i = threadIdx.x; i < HW2D / 8; i += 256) {
        const ushort4* p = (const ushort4*)(yp + i * 8);
        ushort4 v0 = p[0], v1 = p[1];
        float f0 = bf2f(v0.x), f1 = bf2f(v0.y), f2 = bf2f(v0.z), f3 = bf2f(v0.w);
        float f4 = bf2f(v1.x), f5 = bf2f(v1.y), f6 = bf2f(v1.z), f7 = bf2f(v1.w);
        s += (f0 + f1 + f2 + f3) + (f4 + f5 + f6 + f7);
        sq = fmaf(f0, f0, sq); sq = fmaf(f1, f1, sq);
        sq = fmaf(f2, f2, sq); sq = fmaf(f3, f3, sq);
        sq = fmaf(f4, f4, sq); sq = fmaf(f5, f5, sq);
        sq = fmaf(f6, f6, sq); sq = fmaf(f7, f7, sq);
    }
#pragma unroll
    for (int off = 32; off; off >>= 1) {
        s += __shfl_xor(s, off, 64);
        sq += __shfl_xor(sq, off, 64);
    }
    __shared__ float ls[4], lq[4];
    int wid = threadIdx.x >> 6;
    if ((threadIdx.x & 63) == 0) { ls[wid] = s; lq[wid] = sq; }
    __syncthreads();
    if (threadIdx.x == 0) {
        sum[bc]   = ls[0] + ls[1] + ls[2] + ls[3];
        sumsq[bc] = lq[0] + lq[1] + lq[2] + lq[3];
    }
}

// ---------------- GN finalize + gate MLP + fused weights ---------------------
__global__ __launch_bounds__(512) void k_gate(const float* __restrict__ sum,
                                              const float* __restrict__ sumsq,
                                              const float* __restrict__ gn_scale,
                                              const float* __restrict__ gn_bias,
                                              const float* __restrict__ w1,
                                              const float* __restrict__ b1,
                                              const float* __restrict__ w2,
                                              const float* __restrict__ b2,
                                              const float* __restrict__ fw,
                                              float* __restrict__ sA,
                                              float* __restrict__ sB,
                                              float* __restrict__ wef) {
    int t = threadIdx.x;          // 0..511 = b*64+c
    int b = t >> 6, c = t & 63;
    __shared__ float sh_sum[512], sh_sq[512], sh_p[512], sh_h[128];
    float s = sum[t], sq = sumsq[t];
    sh_sum[t] = s;
    sh_sq[t] = sq;
    __syncthreads();
    int base = (t & ~7);
    float gs = 0.f, gq = 0.f;
#pragma unroll
    for (int i = 0; i < 8; ++i) { gs += sh_sum[base + i]; gq += sh_sq[base + i]; }
    const float invN = 1.0f / (8.0f * HW2D);
    float mean = gs * invN;
    float var = gq * invN - mean * mean;
    float rstd = rsqrtf(var + 1e-5f);
    float A = rstd * gn_scale[c];
    float Bv = gn_bias[c] - mean * A;
    sA[t] = A;
    sB[t] = Bv;
    float chmean = s * (1.0f / HW2D);
    sh_p[t] = chmean * A + Bv;
    __syncthreads();
    if (t < 128) {
        int bb = t >> 4, j = t & 15;
        float h = b1[j];
        for (int i = 0; i < 64; ++i) h = fmaf(sh_p[bb * 64 + i], w1[j * 64 + i], h);
        sh_h[t] = fmaxf(h, 0.f);
    }
    __syncthreads();
    float gacc = b2[c];
#pragma unroll
    for (int j = 0; j < 16; ++j) gacc = fmaf(sh_h[b * 16 + j], w2[c * 16 + j], gacc);
    float gamma = 1.0f / (1.0f + expf(-gacc));
    wef[t] = fw[c] + gamma * fw[CR + c];
}

// ------- stencil + partial channel reduce (16 channels per block) ------------
// tiles: 16 rows x 32 cols; halo 18x36 (float, affine applied) in LDS, dbuf
__global__ __launch_bounds__(256) void k_stencil(const unsigned short* __restrict__ y0,
                                                 const float* __restrict__ sA,
                                                 const float* __restrict__ sB,
                                                 const float* __restrict__ wef,
                                                 float* __restrict__ pbuf) {
    const int tw = blockIdx.x * 32, th = blockIdx.y * 16;
    const int b = blockIdx.z & 7, q = blockIdx.z >> 3;
    const int c0 = q * 16;
    __shared__ float sm[2][18 * 36];
    int t = threadIdx.x;
    int col = t & 31, row0 = t >> 5;
    float logit0 = 0.f, logit1 = 0.f;
    const unsigned short* yb = y0 + (size_t)b * CR * HW2D;

    auto stage = [&](int c, int buf) {
        const unsigned short* yc = yb + (size_t)c * HW2D;
        float A = sA[b * 64 + c], Bv = sB[b * 64 + c];
        for (int i = t; i < 18 * 18; i += 256) {       // 18 rows x 18 ushort2
            int r = i / 18, u = i - r * 18;
            int gh = th + r - 1;
            int gw0 = tw - 2 + u * 2;
            float s0 = 0.f, s1 = 0.f;                  // zero-pad AFTER affine
            if ((unsigned)gh < 160u) {
                const unsigned short* rowp = yc + gh * W_;
                if ((unsigned)gw0 < 159u) {            // both lanes in-bounds
                    ushort2 v = *(const ushort2*)(rowp + gw0);
                    s0 = fmaf(A, bf2f(v.x), Bv);
                    s1 = fmaf(A, bf2f(v.y), Bv);
                } else {
                    if ((unsigned)gw0 < 160u)       s0 = fmaf(A, bf2f(rowp[gw0]), Bv);
                    if ((unsigned)(gw0 + 1) < 160u) s1 = fmaf(A, bf2f(rowp[gw0 + 1]), Bv);
                }
            }
            float* d = sm[buf] + r * 36 + u * 2;
            d[0] = s0;
            d[1] = s1;
        }
    };
    stage(c0, 0);
    __syncthreads();
    for (int ci = 0; ci < 16; ++ci) {
        int c = c0 + ci;
        if (ci < 15) stage(c + 1, (ci + 1) & 1);
        float wf = wef[b * 64 + c];
        const float* smc = sm[ci & 1];
#pragma unroll
        for (int k = 0; k < 2; ++k) {
            int r = row0 + k * 8;
            const float* p = smc + r * 36 + col + 1;   // 3x3 around (r+1, col+2)
            float v00 = p[0],  v01 = p[1],  v02 = p[2];
            float v10 = p[36], v11 = p[37], v12 = p[38];
            float v20 = p[72], v21 = p[73], v22 = p[74];
            float mu = (v00 + v01 + v02 + v10 + v11 + v12 + v20 + v21 + v22) * (1.f / 9.f);
            float gx = (v00 - v02 + 2.f * (v10 - v12) + v20 - v22) * 0.25f;
            float gy = (v00 - v20 + 2.f * (v01 - v21) + v02 - v22) * 0.25f;
            float ratio = fminf(fabsf(v11 - mu) / (fabsf(gx) + fabsf(gy) + 1e-4f), 2.f);
            float kap = 1.f - ratio;
            if (k == 0) logit0 = fmaf(wf, kap, logit0);
            else        logit1 = fmaf(wf, kap, logit1);
        }
        __syncthreads();
    }
    float* pb = pbuf + ((size_t)q * NB + b) * HW2D;
    int r0 = th + row0, cpx = tw + col;
    pb[r0 * W_ + cpx]       = logit0;
    pb[(r0 + 8) * W_ + cpx] = logit1;
}

// ---------------- a = sigmoid(p0+p1+p2+p3) -----------------------------------
__global__ __launch_bounds__(256) void k_fuse(const float* __restrict__ pbuf,
                                              float* __restrict__ abuf) {
    int i = blockIdx.x * 256 + threadIdx.x;   // < NB*HW2D/4
    if (i >= NB * HW2D / 4) return;
    const float4* p4 = (const float4*)pbuf;
    float4 q0 = p4[i];
    float4 q1 = p4[2 * NB * HW2D / 4 - NB * HW2D / 4 + i];      // quarter 1
    float4 q2 = p4[2 * NB * HW2D / 4 + i];                      // quarter 2
    float4 q3 = p4[3 * NB * HW2D / 4 + i];                      // quarter 3
    float4 a;
    a.x = 1.f / (1.f + expf(-(q0.x + q1.x + q2.x + q3.x)));
    a.y = 1.f / (1.f + expf(-(q0.y + q1.y + q2.y + q3.y)));
    a.z = 1.f / (1.f + expf(-(q0.z + q1.z + q2.z + q3.z)));
    a.w = 1.f / (1.f + expf(-(q0.w + q1.w + q2.w + q3.w)));
    ((float4*)abuf)[i] = a;
}

// ---------------- out = x * (1 + 0.1*a), div-free grid mapping ---------------
__global__ __launch_bounds__(256) void k_apply(const float* __restrict__ x,
                                               const float* __restrict__ abuf,
                                               float* __restrict__ out) {
    int px4 = blockIdx.x * 256 + threadIdx.x;   // 0..6399
    int c = blockIdx.y, b = blockIdx.z;
    size_t xi = ((size_t)(b * NC + c)) * (HW2D / 4) + px4;
    float4 xv = ((const float4*)x)[xi];
    float4 av = ((const float4*)abuf)[b * (HW2D / 4) + px4];
    float4 ov;
    ov.x = xv.x * fmaf(0.1f, av.x, 1.f);
    ov.y = xv.y * fmaf(0.1f, av.y, 1.f);
    ov.z = xv.z * fmaf(0.1f, av.z, 1.f);
    ov.w = xv.w * fmaf(0.1f, av.w, 1.f);
    ((float4*)out)[xi] = ov;
}

extern "C" void kernel_launch(void* const* d_in, const int* in_sizes, int n_in,
                              void* d_out, int out_size, void* d_ws, size_t ws_size,
                              hipStream_t stream) {
    const float* x   = (const float*)d_in[0];
    const float* rw  = (const float*)d_in[1];
    const float* gns = (const float*)d_in[2];
    const float* gnb = (const float*)d_in[3];
    const float* w1  = (const float*)d_in[4];
    const float* b1  = (const float*)d_in[5];
    const float* w2  = (const float*)d_in[6];
    const float* b2  = (const float*)d_in[7];
    const float* fw  = (const float*)d_in[8];
    float* out = (float*)d_out;

    float* ws    = (float*)d_ws;
    float* pbuf  = ws;                               // 4*8*25600 = 819200 f
    float* abuf  = pbuf + 4 * (size_t)NB * HW2D;     // 204800 f
    float* sum   = abuf + (size_t)NB * HW2D;         // 512
    float* sumsq = sum + 512;
    float* sA    = sumsq + 512;
    float* sB    = sA + 512;
    float* wef   = sB + 512;
    short* aPack = (short*)(wef + 512);              // 16384 shorts (32 KB)
    unsigned short* y0 = (unsigned short*)(aPack + 16384);  // 13,107,200 ushorts

    hipLaunchKernelGGL(k_pack,    dim3(8),          dim3(256), 0, stream, rw, aPack);
    hipLaunchKernelGGL(k_rmfma,   dim3(1600),       dim3(256), 0, stream, x, aPack, y0);
    hipLaunchKernelGGL(k_stats,   dim3(512),        dim3(256), 0, stream, y0, sum, sumsq);
    hipLaunchKernelGGL(k_gate,    dim3(1),          dim3(512), 0, stream,
                       sum, sumsq, gns, gnb, w1, b1, w2, b2, fw, sA, sB, wef);
    hipLaunchKernelGGL(k_stencil, dim3(5, 10, 32),  dim3(256), 0, stream, y0, sA, sB, wef, pbuf);
    hipLaunchKernelGGL(k_fuse,    dim3(200),        dim3(256), 0, stream, pbuf, abuf);
    hipLaunchKernelGGL(k_apply,   dim3(25, 256, 8), dim3(256), 0, stream, x, abuf, out);
}